// Round 12
// baseline (375.222 us; speedup 1.0000x reference)
//
#include <hip/hip_runtime.h>
#include <hip/hip_bf16.h>

#define BATCH 128
#define SGRID 32
#define NCELL 1024
#define NTOT  1025
#define FD    128
#define NACT  19
#define NEG_INF_F  (-3.4028234663852886e38f)  // jnp.finfo(float32).min
#define BF16_SAFE_F (3.3e38f)                 // < bf16 max finite (3.3895e38)

typedef unsigned short ushort_t;
typedef unsigned int   uint_t;
typedef short   short8   __attribute__((ext_vector_type(8)));
typedef float   floatx16 __attribute__((ext_vector_type(16)));
typedef float   floatx2  __attribute__((ext_vector_type(2)));

__device__ __forceinline__ float elu_fast(float v) {   // bf16-accurate ELU
    return v > 0.f ? v : (__expf(v) - 1.f);
}
__device__ __forceinline__ float bf2f(ushort_t h) {
    union { uint_t u; float f; } v; v.u = ((uint_t)h) << 16; return v.f;
}
__device__ __forceinline__ ushort_t f2bf(float f) {   // round-to-nearest-even
    union { float f; uint_t u; } v; v.f = f;
    uint_t r = v.u + 0x7FFFu + ((v.u >> 16) & 1u);
    return (ushort_t)(r >> 16);
}
__device__ __forceinline__ uint_t pkbf(float a, float b) {  // v_cvt_pk_bf16_f32
    union { __hip_bfloat162 h; uint_t u; } v;
    v.h = __float22bfloat162_rn(make_float2(a, b));
    return v.u;
}
__device__ __forceinline__ floatx2 up2(uint_t u) {    // 2 bf16 -> float2
    union { uint_t x; float f; } lo, hi;
    lo.x = u << 16; hi.x = u & 0xFFFF0000u;
    floatx2 r; r.x = lo.f; r.y = hi.f; return r;
}
__device__ __forceinline__ void unpack2(uint_t u, float& a, float& b) {
    union { uint_t x; float f; } lo, hi;
    lo.x = u << 16; hi.x = u & 0xFFFF0000u;
    a = lo.f; b = hi.f;
}
__device__ __forceinline__ void unpack8(uint4 v, float* f) {
    unpack2(v.x, f[0], f[1]); unpack2(v.y, f[2], f[3]);
    unpack2(v.z, f[4], f[5]); unpack2(v.w, f[6], f[7]);
}
__device__ __forceinline__ void unpack4(uint2 v, float* f) {
    unpack2(v.x, f[0], f[1]); unpack2(v.y, f[2], f[3]);
}

// ---------------------------------------------------------------------------
// Pack GNN weights into MFMA B-fragment order for v_mfma_f32_32x32x16_bf16:
// B[k][n], lane layout n = lane&31, k = (lane>>5)*8 + j (j=0..7).
// group g = ((layer*2 + p)*4 + ntile)*8*64 + ks*64 + lane; p=0:Ws, p=1:Wn.
// ---------------------------------------------------------------------------
__global__ __launch_bounds__(256) void gnn_setup_frags(
    const ushort_t* __restrict__ Ws,   // 3 x 128 x 128, k-major
    const ushort_t* __restrict__ Wn,
    ushort_t* __restrict__ wfrag)
{
    const int g = blockIdx.x * 256 + threadIdx.x;   // 12288 groups
    if (g >= 3 * 2 * 4 * 8 * 64) return;
    const int lane = g & 63;
    const int ks   = (g >> 6) & 7;
    const int nt   = (g >> 9) & 3;
    const int p    = (g >> 11) & 1;
    const int l    = g >> 12;
    const ushort_t* W = (p ? Wn : Ws) + (size_t)l * FD * FD;
    const int k0  = ks * 16 + (lane >> 5) * 8;
    const int col = nt * 32 + (lane & 31);
    ushort_t v[8];
    #pragma unroll
    for (int j = 0; j < 8; ++j) v[j] = W[(size_t)(k0 + j) * FD + col];
    uint4 u;
    u.x = v[0] | ((uint_t)v[1] << 16); u.y = v[2] | ((uint_t)v[3] << 16);
    u.z = v[4] | ((uint_t)v[5] << 16); u.w = v[6] | ((uint_t)v[7] << 16);
    *(uint4*)(wfrag + (size_t)g * 8) = u;
}

// ---------------------------------------------------------------------------
// GEMM: [U|V] = X @ [Ws|Wn].  M = B*1025 = 131200 = 1025 m-tiles of 128 rows
// (tiles cross batch boundaries — rows are independent).  Each block: one
// 128-row m-tile x one 128-col half (nsel 0 = U/Ws, 1 = V/Wn), K=128.
// A and B staged in LDS in MFMA-FRAGMENT ORDER: K-loop b128 reads are fully
// conflict-free (contiguous 1 KB per wave instr); the A staging write uses a
// lane ^= (ks<<2) swizzle so its 16-thread groups spread across 8 bank-groups
// (2-way = free) instead of 16-way-conflicting.  Minimal chain: batch loads ->
// barrier -> 32 MFMA/wave -> barrier -> LDS repack -> coalesced stores.
// ---------------------------------------------------------------------------
__global__ __launch_bounds__(256, 2) void gnn_gemm(
    const ushort_t* __restrict__ xin,    // layer input (bf16)
    ushort_t* __restrict__ uv,           // out: B*1025 rows x 256 (U|V)
    const ushort_t* __restrict__ wfragL, // this layer's 2x32KB fragment block
    int div1025)                         // 1: xin is gmap (B*1024*128, no meta)
{
    const int mtile = blockIdx.x >> 1;   // 0..1024
    const int nsel  = blockIdx.x & 1;
    const int t = threadIdx.x;
    const int w = t >> 6, l = t & 63;

    __shared__ alignas(16) ushort_t af[16384];  // 32 KB A frags / C out tile
    __shared__ alignas(16) ushort_t bf[16384];  // 32 KB B frags

    const uint4 zero4 = make_uint4(0u, 0u, 0u, 0u);

    // Batch ALL global loads (A coalesced row-major; B linear frag copy).
    uint4 aT[8], bT[8];
    #pragma unroll
    for (int jj = 0; jj < 8; ++jj) {
        const int cid = t + 256 * jj;          // 0..2047
        const int row = cid >> 4, ch = cid & 15;
        const int gr = mtile * 128 + row;
        if (div1025) {
            const int bb = gr / 1025, node = gr - bb * 1025;
            aT[jj] = (node < NCELL)
                ? *(const uint4*)(xin + ((size_t)(bb * NCELL + node) * FD + ch * 8))
                : zero4;
        } else {
            aT[jj] = *(const uint4*)(xin + ((size_t)gr * FD + ch * 8));
        }
    }
    const ushort_t* WB = wfragL + nsel * 16384;
    #pragma unroll
    for (int jj = 0; jj < 8; ++jj)
        bT[jj] = *(const uint4*)(WB + (size_t)(t + 256 * jj) * 8);

    // Stage to LDS in fragment order (A write-swizzled).
    #pragma unroll
    for (int jj = 0; jj < 8; ++jj) {
        const int cid = t + 256 * jj;
        const int row = cid >> 4, ch = cid & 15;
        const int mt = row >> 5, lane_lo = row & 31;
        const int ks = ch >> 1, hi = ch & 1;
        const int lane = (hi * 32 + lane_lo) ^ (ks << 2);
        *(uint4*)&af[((mt * 8 + ks) * 64 + lane) * 8] = aT[jj];
    }
    #pragma unroll
    for (int jj = 0; jj < 8; ++jj)
        *(uint4*)&bf[(size_t)(t + 256 * jj) * 8] = bT[jj];
    __syncthreads();

    // K-loop: pure LDS b128 + MFMA. Wave w owns 32 cols; 4 m-tiles.
    floatx16 acc[4];
    #pragma unroll
    for (int mt = 0; mt < 4; ++mt)
        #pragma unroll
        for (int q = 0; q < 16; ++q) acc[mt][q] = 0.f;

    #pragma unroll
    for (int ks = 0; ks < 8; ++ks) {
        const short8 bb = *(const short8*)&bf[((w * 8 + ks) * 64 + l) * 8];
        #pragma unroll
        for (int mt = 0; mt < 4; ++mt) {
            const short8 aa = *(const short8*)&af[((mt * 8 + ks) * 64 + (l ^ (ks << 2))) * 8];
            acc[mt] = __builtin_amdgcn_mfma_f32_32x32x16_bf16(aa, bb, acc[mt], 0, 0, 0);
        }
    }
    __syncthreads();

    // Repack C/D (col=lane&31, row=(r&3)+8*(r>>2)+4*(lane>>5)) into af as a
    // natural [row][col] 128x128 bf16 tile, then coalesced uint4 stores.
    const int colT = w * 32 + (l & 31);
    #pragma unroll
    for (int mt = 0; mt < 4; ++mt)
        #pragma unroll
        for (int r = 0; r < 16; ++r) {
            const int rowC = mt * 32 + (r & 3) + 8 * (r >> 2) + 4 * (l >> 5);
            af[rowC * 128 + colT] = f2bf(acc[mt][r]);
        }
    __syncthreads();
    #pragma unroll
    for (int jj = 0; jj < 8; ++jj) {
        const int cid = t + 256 * jj;
        const int row = cid >> 4, ch = cid & 15;
        const int gr = mtile * 128 + row;
        *(uint4*)(uv + (size_t)gr * 256 + nsel * 128 + ch * 8) =
            *(const uint4*)&af[row * 128 + ch * 8];
    }
}

// ---------------------------------------------------------------------------
// Stencil epilogue: y = elu(U + V[up]+V[down]+V[left]+V[right] + V[meta] + bs)
// per cell; y_meta = elu(U_meta + Sum_cells V + bs).  (V of layer-1 meta row
// is 0 since its x was 0 -> adding it is always correct; no meta_valid flag.)
// Grid 17*128, XCD-swizzled so a batch's blocks share an XCD L2.
// rb<16: 2 grid rows (64 cells); rb==16: meta reduction.  LDS 33 KB.
// ---------------------------------------------------------------------------
__global__ __launch_bounds__(256, 4) void gnn_stencil(
    const ushort_t* __restrict__ uv,     // B*1025 x 256 (U|V)
    ushort_t* __restrict__ y,            // B*1025 x 128
    const ushort_t* __restrict__ bs)     // this layer's bias (128)
{
    const int i = blockIdx.x;
    const int xcd = i & 7;
    const int j = i >> 3;
    const int b = xcd * 16 + j / 17;
    const int rb = j % 17;
    const int t = threadIdx.x;
    const ushort_t* uvb = uv + (size_t)b * NTOT * 256;
    ushort_t* yb = y + (size_t)b * NTOT * FD;

    __shared__ alignas(16) ushort_t vlds[4 * 32 * 128];  // 32 KB V rows
    __shared__ alignas(16) ushort_t vm[FD];              // V meta row
    __shared__ alignas(16) ushort_t bsl[FD];             // bias

    if (rb == 16) {
        // ---- meta: y_meta = elu(U_meta + Sum_{1024 cells} V + bs) ----
        float* part = (float*)vlds;            // 16 x 128 partials
        const int kc = (t & 15) * 8;
        const int cg = t >> 4;
        float s[8];
        #pragma unroll
        for (int q = 0; q < 8; ++q) s[q] = 0.f;
        #pragma unroll 4
        for (int n = 0; n < 64; ++n) {
            const int cell = cg * 64 + n;
            float f[8];
            unpack8(*(const uint4*)(uvb + (size_t)cell * 256 + 128 + kc), f);
            #pragma unroll
            for (int q = 0; q < 8; ++q) s[q] += f[q];
        }
        #pragma unroll
        for (int q = 0; q < 8; ++q) part[cg * FD + kc + q] = s[q];
        __syncthreads();
        if (t < FD) {
            float a = bf2f(uvb[(size_t)NCELL * 256 + t]) + bf2f(bs[t]);
            #pragma unroll
            for (int gI = 0; gI < 16; ++gI) a += part[gI * FD + t];
            yb[(size_t)NCELL * FD + t] = f2bf(elu_fast(a));
        }
        return;
    }

    const int r0 = rb * 2;

    // Batch ALL loads: V rows r0-1..r0+2 (zero-filled OOB), U tile (regs),
    // V meta row, bias.
    uint4 vT[8], uT[4];
    const uint4 zero4 = make_uint4(0u, 0u, 0u, 0u);
    #pragma unroll
    for (int jj = 0; jj < 8; ++jj) {
        const int cid = t + 256 * jj;          // 0..2047
        const int vr = cid >> 9;               // 0..3 -> grid row r0-1+vr
        const int c = (cid >> 4) & 31, ch = cid & 15;
        const int grow = r0 - 1 + vr;
        vT[jj] = (grow >= 0 && grow < SGRID)
            ? *(const uint4*)(uvb + (size_t)(grow * SGRID + c) * 256 + 128 + ch * 8)
            : zero4;
    }
    #pragma unroll
    for (int jj = 0; jj < 4; ++jj) {
        const int cid = t + 256 * jj;          // 0..1023
        const int cc = cid >> 4, ch = cid & 15;
        uT[jj] = *(const uint4*)(uvb + (size_t)(r0 * SGRID + cc) * 256 + ch * 8);
    }
    if (t < 16) {
        *(uint4*)&vm[t * 8]  = *(const uint4*)(uvb + (size_t)NCELL * 256 + 128 + t * 8);
        *(uint4*)&bsl[t * 8] = *(const uint4*)(bs + t * 8);
    }
    #pragma unroll
    for (int jj = 0; jj < 8; ++jj)
        *(uint4*)&vlds[(size_t)(t + 256 * jj) * 8] = vT[jj];
    __syncthreads();

    // Compute 4 output chunks per thread.
    #pragma unroll
    for (int jj = 0; jj < 4; ++jj) {
        const int cid = t + 256 * jj;
        const int cc = cid >> 4, ch = cid & 15;
        const int lr = cc >> 5, c = cc & 31;
        const int k8 = ch * 8;
        // up (vlds row lr), down (lr+2), laterals (lr+1, c+-1)
        uint4 upv = *(const uint4*)&vlds[((lr) * 32 + c) * 128 + k8];
        uint4 dnv = *(const uint4*)&vlds[((lr + 2) * 32 + c) * 128 + k8];
        floatx2 s0 = up2(upv.x) + up2(dnv.x);
        floatx2 s1 = up2(upv.y) + up2(dnv.y);
        floatx2 s2 = up2(upv.z) + up2(dnv.z);
        floatx2 s3 = up2(upv.w) + up2(dnv.w);
        if (c > 0) {
            uint4 L = *(const uint4*)&vlds[((lr + 1) * 32 + c - 1) * 128 + k8];
            s0 += up2(L.x); s1 += up2(L.y); s2 += up2(L.z); s3 += up2(L.w);
        }
        if (c < 31) {
            uint4 R = *(const uint4*)&vlds[((lr + 1) * 32 + c + 1) * 128 + k8];
            s0 += up2(R.x); s1 += up2(R.y); s2 += up2(R.z); s3 += up2(R.w);
        }
        uint4 M = *(const uint4*)&vm[k8];
        s0 += up2(M.x); s1 += up2(M.y); s2 += up2(M.z); s3 += up2(M.w);
        uint4 Bv = *(const uint4*)&bsl[k8];
        s0 += up2(Bv.x); s1 += up2(Bv.y); s2 += up2(Bv.z); s3 += up2(Bv.w);
        s0 += up2(uT[jj].x); s1 += up2(uT[jj].y);
        s2 += up2(uT[jj].z); s3 += up2(uT[jj].w);
        uint4 o;
        o.x = pkbf(elu_fast(s0.x), elu_fast(s0.y));
        o.y = pkbf(elu_fast(s1.x), elu_fast(s1.y));
        o.z = pkbf(elu_fast(s2.x), elu_fast(s2.y));
        o.w = pkbf(elu_fast(s3.x), elu_fast(s3.y));
        *(uint4*)(yb + (size_t)((r0 + lr) * SGRID + c) * FD + k8) = o;
    }
}

// ---------------------------------------------------------------------------
// Head: gather + 6-layer MLP + mask. 128 blocks (XCD-swizzled, 1 batch each)
// x 1024 threads = 16 waves doing a 16-way K-split; partials reduced via
// part[16][512] in LDS. LDS ~39 KB.
// ---------------------------------------------------------------------------
__global__ __launch_bounds__(1024) void head_kernel(
    const ushort_t* __restrict__ x,       // bf16, B x 1025 x 128
    const int* __restrict__ pos,
    const int* __restrict__ amask,
    const ushort_t* __restrict__ Wd1, const ushort_t* __restrict__ bd1,
    const ushort_t* __restrict__ Wd2, const ushort_t* __restrict__ bd2,
    const ushort_t* __restrict__ Wd3, const ushort_t* __restrict__ bd3,
    const ushort_t* __restrict__ Wp1, const ushort_t* __restrict__ bp1,
    const ushort_t* __restrict__ Wp2, const ushort_t* __restrict__ bp2,
    const ushort_t* __restrict__ Wp3, const ushort_t* __restrict__ bp3,
    ushort_t* __restrict__ out)           // bf16, B x 19
{
    const int t = threadIdx.x;
    const int b = (blockIdx.x & 7) * 16 + (blockIdx.x >> 3);  // batch on its XCD
    const int q = t >> 6;             // K-split sixteenth (wave id, 0..15)
    const int lane = t & 63;

    __shared__ float st[640];
    __shared__ float bufA[512];
    __shared__ float bufB[512];
    __shared__ float part[16][512];

    const int OFFR[5] = {-1, 0, 1, 0, 0};
    const int OFFC[5] = {0, -1, 0, 1, 0};

    // Gather state (reference's j=(pos+off+1)@[32,1] into 34-wide padded map).
    {
        const int pr = pos[b * 2 + 0], pc = pos[b * 2 + 1];
        for (int e = t; e < 640; e += 1024) {
            const int slot = e >> 7, k = e & 127;
            const int jj = (pr + OFFR[slot] + 1) * SGRID + (pc + OFFC[slot] + 1);
            const int qr = jj / (SGRID + 2), qc = jj % (SGRID + 2);
            float v = 0.f;
            if (qr >= 1 && qr <= SGRID && qc >= 1 && qc <= SGRID)
                v = bf2f(x[((size_t)b * NTOT + (qr - 1) * SGRID + (qc - 1)) * FD + k]);
            st[e] = v;
        }
    }
    __syncthreads();

    // ---- L1: 640 -> 512 (K/16 = 40 per wave; lane owns 8 cols) ----
    {
        float acc[8];
        #pragma unroll
        for (int p = 0; p < 8; ++p) acc[p] = 0.f;
        const int c0 = lane * 8;
        const int kb = q * 40;
        #pragma unroll 8
        for (int k = kb; k < kb + 40; ++k) {
            const float s = st[k];
            float f[8]; unpack8(*(const uint4*)(Wd1 + (size_t)k * 512 + c0), f);
            #pragma unroll
            for (int p = 0; p < 8; ++p) acc[p] += s * f[p];
        }
        #pragma unroll
        for (int p = 0; p < 8; ++p) part[q][c0 + p] = acc[p];
        __syncthreads();
        if (t < 512) {
            float a = bf2f(bd1[t]);
            #pragma unroll
            for (int p = 0; p < 16; ++p) a += part[p][t];
            bufA[t] = elu_fast(a);
        }
        __syncthreads();
    }
    // ---- L2: 512 -> 512 (K/16 = 32) ----
    {
        float acc[8];
        #pragma unroll
        for (int p = 0; p < 8; ++p) acc[p] = 0.f;
        const int c0 = lane * 8;
        const int kb = q * 32;
        #pragma unroll 8
        for (int k = kb; k < kb + 32; ++k) {
            const float s = bufA[k];
            float f[8]; unpack8(*(const uint4*)(Wd2 + (size_t)k * 512 + c0), f);
            #pragma unroll
            for (int p = 0; p < 8; ++p) acc[p] += s * f[p];
        }
        #pragma unroll
        for (int p = 0; p < 8; ++p) part[q][c0 + p] = acc[p];
        __syncthreads();
        if (t < 512) {
            float a = bf2f(bd2[t]);
            #pragma unroll
            for (int p = 0; p < 16; ++p) a += part[p][t];
            bufB[t] = elu_fast(a);
        }
        __syncthreads();
    }
    // ---- L3: 512 -> 256 (K/16 = 32; out -> st[0..255]) ----
    {
        float acc[4];
        #pragma unroll
        for (int p = 0; p < 4; ++p) acc[p] = 0.f;
        const int c0 = lane * 4;
        const int kb = q * 32;
        #pragma unroll 8
        for (int k = kb; k < kb + 32; ++k) {
            const float s = bufB[k];
            float f[4]; unpack4(*(const uint2*)(Wd3 + (size_t)k * 256 + c0), f);
            #pragma unroll
            for (int p = 0; p < 4; ++p) acc[p] += s * f[p];
        }
        #pragma unroll
        for (int p = 0; p < 4; ++p) part[q][c0 + p] = acc[p];
        __syncthreads();
        if (t < 256) {
            float a = bf2f(bd3[t]);
            #pragma unroll
            for (int p = 0; p < 16; ++p) a += part[p][t];
            st[t] = elu_fast(a);
        }
        __syncthreads();
    }
    // ---- L4: 256 -> 256 (K/16 = 16; st -> bufA) ----
    {
        float acc[4];
        #pragma unroll
        for (int p = 0; p < 4; ++p) acc[p] = 0.f;
        const int c0 = lane * 4;
        const int kb = q * 16;
        #pragma unroll 8
        for (int k = kb; k < kb + 16; ++k) {
            const float s = st[k];
            float f[4]; unpack4(*(const uint2*)(Wp1 + (size_t)k * 256 + c0), f);
            #pragma unroll
            for (int p = 0; p < 4; ++p) acc[p] += s * f[p];
        }
        #pragma unroll
        for (int p = 0; p < 4; ++p) part[q][c0 + p] = acc[p];
        __syncthreads();
        if (t < 256) {
            float a = bf2f(bp1[t]);
            #pragma unroll
            for (int p = 0; p < 16; ++p) a += part[p][t];
            bufA[t] = elu_fast(a);
        }
        __syncthreads();
    }
    // ---- L5: 256 -> 256 (bufA -> bufB) ----
    {
        float acc[4];
        #pragma unroll
        for (int p = 0; p < 4; ++p) acc[p] = 0.f;
        const int c0 = lane * 4;
        const int kb = q * 16;
        #pragma unroll 8
        for (int k = kb; k < kb + 16; ++k) {
            const float s = bufA[k];
            float f[4]; unpack4(*(const uint2*)(Wp2 + (size_t)k * 256 + c0), f);
            #pragma unroll
            for (int p = 0; p < 4; ++p) acc[p] += s * f[p];
        }
        #pragma unroll
        for (int p = 0; p < 4; ++p) part[q][c0 + p] = acc[p];
        __syncthreads();
        if (t < 256) {
            float a = bf2f(bp2[t]);
            #pragma unroll
            for (int p = 0; p < 16; ++p) a += part[p][t];
            bufB[t] = elu_fast(a);
        }
        __syncthreads();
    }
    // ---- L6: 256 -> 19 + mask, finite-clamped bf16 ----
    {
        float a = 0.f;
        const int kb = q * 16;
        if (lane < NACT) {
            #pragma unroll 8
            for (int k = kb; k < kb + 16; ++k)
                a += bufB[k] * bf2f(Wp3[(size_t)k * NACT + lane]);
            part[q][lane] = a;
        }
        __syncthreads();
        if (t < NACT) {
            float v = bf2f(bp3[t]);
            #pragma unroll
            for (int p = 0; p < 16; ++p) v += part[p][t];
            v += amask[b * NACT + t] ? 0.f : NEG_INF_F;
            v = fminf(fmaxf(v, -BF16_SAFE_F), BF16_SAFE_F);
            out[b * NACT + t] = f2bf(v);
        }
    }
}

extern "C" void kernel_launch(void* const* d_in, const int* in_sizes, int n_in,
                              void* d_out, int out_size, void* d_ws, size_t ws_size,
                              hipStream_t stream) {
    const ushort_t* gmap  = (const ushort_t*)d_in[0];
    const int*      pos   = (const int*)     d_in[1];
    const int*      amask = (const int*)     d_in[2];
    const ushort_t* Ws    = (const ushort_t*)d_in[3];
    const ushort_t* Wn    = (const ushort_t*)d_in[4];
    const ushort_t* bs    = (const ushort_t*)d_in[5];
    const ushort_t* Wd1   = (const ushort_t*)d_in[6];
    const ushort_t* bd1   = (const ushort_t*)d_in[7];
    const ushort_t* Wd2   = (const ushort_t*)d_in[8];
    const ushort_t* bd2   = (const ushort_t*)d_in[9];
    const ushort_t* Wd3   = (const ushort_t*)d_in[10];
    const ushort_t* bd3   = (const ushort_t*)d_in[11];
    const ushort_t* Wp1   = (const ushort_t*)d_in[12];
    const ushort_t* bp1   = (const ushort_t*)d_in[13];
    const ushort_t* Wp2   = (const ushort_t*)d_in[14];
    const ushort_t* bp2   = (const ushort_t*)d_in[15];
    const ushort_t* Wp3   = (const ushort_t*)d_in[16];
    const ushort_t* bp3   = (const ushort_t*)d_in[17];

    // Workspace: uv (67.2 MB) + x1/x2 (33.6 MB each) + wfrag (192 KB).
    ushort_t* uv = (ushort_t*)d_ws;
    ushort_t* x1 = uv + (size_t)BATCH * NTOT * 256;
    ushort_t* x2 = x1 + (size_t)BATCH * NTOT * FD;
    ushort_t* wfrag = x2 + (size_t)BATCH * NTOT * FD;

    gnn_setup_frags<<<48, 256, 0, stream>>>(Ws, Wn, wfrag);

    const int ngemm = 1025 * 2;
    const int nsten = 17 * BATCH;

    // Layer 1 (input gmap: B x 1024 x 128, meta rows read as zero)
    gnn_gemm<<<ngemm, 256, 0, stream>>>(gmap, uv, wfrag, 1);
    gnn_stencil<<<nsten, 256, 0, stream>>>(uv, x1, bs);
    // Layer 2
    gnn_gemm<<<ngemm, 256, 0, stream>>>(x1, uv, wfrag + 32768, 0);
    gnn_stencil<<<nsten, 256, 0, stream>>>(uv, x2, bs + FD);
    // Layer 3
    gnn_gemm<<<ngemm, 256, 0, stream>>>(x2, uv, wfrag + 65536, 0);
    gnn_stencil<<<nsten, 256, 0, stream>>>(uv, x1, bs + 2 * FD);

    head_kernel<<<BATCH, 1024, 0, stream>>>(x1, pos, amask,
                                            Wd1, bd1, Wd2, bd2, Wd3, bd3,
                                            Wp1, bp1, Wp2, bp2, Wp3, bp3,
                                            (ushort_t*)d_out);
}